// Round 13
// baseline (416.754 us; speedup 1.0000x reference)
//
#include <hip/hip_runtime.h>

// ---------------------------------------------------------------------------
// VQEmbeddingEMA forward on MI355X (gfx950), fp32.
//   N = 32*2048 = 65536 tokens, D = 64, K = 1024 codes.
// Round 13 = round 12 with the compile fix (plain float4 store; clang rejects
// __builtin_nontemporal_store on HIP_vector_type). 8x4 register tile
// (128-token block x 64-code e-tiles) -> 12 LDS reads per 128 FMA (round 11
// was LDS-pipe-bound at 8 per 64, VALUBusy 47%). x-side LDS offsets
// immediate-folded; e-side 1 XOR. Merge buffers stride-17 (round-11's 1.1M
// bank conflicts). Gather = scan/scatter/gather2 token lists.
// ---------------------------------------------------------------------------

#define N_TOK   65536
#define KCODES  1024

#define Q_OFF   0
#define SC_OFF  4194304
#define NE_OFF  4194307
#define NC_OFF  4259843
#define NW_OFF  4260867
#define NU_OFF  4326403

// ws layout (floats/ints)
#define WS_COUNTS 0              // [1024] float (atomic, zeroed)
#define WS_LOSS   1024           // [1]    float (atomic, zeroed)
#define WS_HN     1028           // [1024] float
#define WS_IDX    2052           // [65536] int
#define WS_OFFS   67588          // [1024] int
#define WS_CURSOR 68612          // [1024] int
#define WS_LIST   69636          // [65536] int

// 0.5 * |e_k|^2 per code
__global__ __launch_bounds__(256) void hn_kernel(const float* __restrict__ emb,
                                                 float* __restrict__ hn) {
    int k = blockIdx.x * 256 + threadIdx.x;   // grid 4x256 -> 1024
    const float4* e4 = reinterpret_cast<const float4*>(emb) + (size_t)k * 16;
    float4 a = make_float4(0.f, 0.f, 0.f, 0.f);
#pragma unroll
    for (int i = 0; i < 16; ++i) {
        float4 e = e4[i];
        a.x = fmaf(e.x, e.x, a.x);
        a.y = fmaf(e.y, e.y, a.y);
        a.z = fmaf(e.z, e.z, a.z);
        a.w = fmaf(e.w, e.w, a.w);
    }
    hn[k] = 0.5f * ((a.x + a.y) + (a.z + a.w));
}

// Block b: tokens [b*128, b*128+128) vs all 1024 codes (16 e-tiles of 64).
// 4 waves: wx = wid&1 token-half (64 tok), wy = wid>>1 code-half (32 codes).
// lane: tg = lane&7, cg = lane>>3. Thread tile: 8 tokens x 4 codes.
// rowx[t] = wx*64 + t*8 + tg (t<8); rowe[c] = wy*32 + c*8 + cg (c<4).
// LDS f4 slot for (row, dim-group j): row*16 + (j ^ (row&7)).
// Inner loop iterates jj = x-slot directly (immediate offsets); matching
// e-slot = jj ^ (tg^cg) (same dim-group j = jj^tg on both sides).
__global__ __launch_bounds__(256, 3) void assign_fused(
    const float* __restrict__ x, const float* __restrict__ emb,
    const float* __restrict__ hn_g, float* __restrict__ counts,
    float* __restrict__ loss_sum, int* __restrict__ idx,
    float* __restrict__ qout) {
    const int b    = blockIdx.x;
    const int tid  = threadIdx.x;
    const int lane = tid & 63;
    const int wid  = tid >> 6;
    const int wx   = wid & 1;
    const int wy   = wid >> 1;
    const int tg   = lane & 7;
    const int cg   = lane >> 3;
    const int exc  = tg ^ cg;

    __shared__ float4 sx4[2048];          // 128 tok x 16 f4, swizzled (32 KB)
    __shared__ float4 se4[1024];          // 64 codes x 16 f4, swizzled (16 KB)
    __shared__ float  shn[64];
    __shared__ float  cand_s[128 * 17];   // stride 17: bank-conflict-free
    __shared__ int    cand_i[128 * 17];
    __shared__ int    sbi[128];

    const float4* __restrict__ gx4 =
        reinterpret_cast<const float4*>(x) + (size_t)b * 2048;
    const float4* __restrict__ ge4 = reinterpret_cast<const float4*>(emb);

    // stage x tile once (coalesced, swizzled store)
#pragma unroll
    for (int i = 0; i < 8; ++i) {
        int f = i * 256 + tid;
        int r = f >> 4, j = f & 15;
        sx4[r * 16 + (j ^ (r & 7))] = gx4[f];
    }

    float best[8], acc[8][4];
    int   bidx[8];
#pragma unroll
    for (int t = 0; t < 8; ++t) { best[t] = 3.0e38f; bidx[t] = 0; }

    for (int et = 0; et < 16; ++et) {
        const int kbase = et * 64;
        __syncthreads();                  // prior tile reads done (covers x)
#pragma unroll
        for (int i = 0; i < 4; ++i) {
            int f = i * 256 + tid;
            int r = f >> 4, j = f & 15;
            se4[r * 16 + (j ^ (r & 7))] = ge4[(size_t)kbase * 16 + f];
        }
        if (tid < 64) shn[tid] = hn_g[kbase + tid];
        __syncthreads();

#pragma unroll
        for (int t = 0; t < 8; ++t)
#pragma unroll
            for (int c = 0; c < 4; ++c) acc[t][c] = 0.0f;

#pragma unroll
        for (int jj = 0; jj < 16; ++jj) {
            float4 xf[8], ef[4];
#pragma unroll
            for (int t = 0; t < 8; ++t)
                xf[t] = sx4[(wx * 64 + t * 8 + tg) * 16 + jj];      // imm off
#pragma unroll
            for (int c = 0; c < 4; ++c)
                ef[c] = se4[(wy * 32 + c * 8 + cg) * 16 + (jj ^ exc)];
#pragma unroll
            for (int t = 0; t < 8; ++t)
#pragma unroll
                for (int c = 0; c < 4; ++c) {
                    acc[t][c] = fmaf(xf[t].x, ef[c].x, acc[t][c]);
                    acc[t][c] = fmaf(xf[t].y, ef[c].y, acc[t][c]);
                    acc[t][c] = fmaf(xf[t].z, ef[c].z, acc[t][c]);
                    acc[t][c] = fmaf(xf[t].w, ef[c].w, acc[t][c]);
                }
        }

#pragma unroll
        for (int c = 0; c < 4; ++c) {
            const int   re   = wy * 32 + c * 8 + cg;
            const float h    = shn[re];
            const int   code = kbase + re;
#pragma unroll
            for (int t = 0; t < 8; ++t) {
                float s = h - acc[t][c];   // argmin_k 0.5|e|^2 - x.e
                if (s < best[t] || (s == best[t] && code < bidx[t])) {
                    best[t] = s; bidx[t] = code;
                }
            }
        }
    }

    // ---- cross-thread merge (tie-aware, lowest code wins) ----
    __syncthreads();
    const int col = wy * 8 + cg;          // 0..15
#pragma unroll
    for (int t = 0; t < 8; ++t) {
        const int rx = wx * 64 + t * 8 + tg;
        cand_s[rx * 17 + col] = best[t];
        cand_i[rx * 17 + col] = bidx[t];
    }
    __syncthreads();
    if (tid < 128) {
        float bs = cand_s[tid * 17];
        int   bi = cand_i[tid * 17];
#pragma unroll
        for (int q = 1; q < 16; ++q) {
            float s2 = cand_s[tid * 17 + q];
            int   i2 = cand_i[tid * 17 + q];
            if (s2 < bs || (s2 == bs && i2 < bi)) { bs = s2; bi = i2; }
        }
        sbi[tid] = bi;
        idx[b * 128 + tid] = bi;
        atomicAdd(&counts[bi], 1.0f);
    }
    __syncthreads();

    // ---- fused epilogue: quantized write + loss ----
    const int tok  = tid >> 1;            // 0..127
    const int half = tid & 1;             // 8 f4 per half-row
    const int bi   = sbi[tok];
    float4* q4 = reinterpret_cast<float4*>(qout) +
                 (size_t)(b * 128 + tok) * 16 + half * 8;
    float lsum = 0.0f;
#pragma unroll
    for (int i = 0; i < 8; ++i) {
        int jf = half * 8 + i;
        float4 ev = ge4[(size_t)bi * 16 + jf];
        float4 xv = sx4[tok * 16 + (jf ^ (tok & 7))];
        q4[i] = ev;
        float d0 = xv.x - ev.x; lsum = fmaf(d0, d0, lsum);
        float d1 = xv.y - ev.y; lsum = fmaf(d1, d1, lsum);
        float d2 = xv.z - ev.z; lsum = fmaf(d2, d2, lsum);
        float d3 = xv.w - ev.w; lsum = fmaf(d3, d3, lsum);
    }
#pragma unroll
    for (int off = 32; off; off >>= 1) lsum += __shfl_down(lsum, off, 64);
    if (lane == 0) atomicAdd(loss_sum, lsum);
}

// exclusive prefix sum of counts -> offs, cursor (one block, 1024 thr)
__global__ __launch_bounds__(1024) void scan_kernel(
    const float* __restrict__ counts, int* __restrict__ offs,
    int* __restrict__ cursor) {
    __shared__ int s[1024];
    const int k = threadIdx.x;
    const int c = (int)counts[k];
    s[k] = c;
    __syncthreads();
    for (int st = 1; st < 1024; st <<= 1) {
        int v = (k >= st) ? s[k - st] : 0;
        __syncthreads();
        s[k] += v;
        __syncthreads();
    }
    const int excl = s[k] - c;
    offs[k] = excl;
    cursor[k] = excl;
}

// one atomic per token: build per-code token lists
__global__ __launch_bounds__(256) void scatter_kernel(
    const int* __restrict__ idx, int* __restrict__ cursor,
    int* __restrict__ list) {
    const int t = blockIdx.x * 256 + threadIdx.x;
    const int k = idx[t];
    const int slot = atomicAdd(&cursor[k], 1);
    list[slot] = t;
}

// counts-based outputs: new_count, new_usage, scalars (one block, k = tid).
// Runs BEFORE gather2 (gather2 reads out[NC_OFF+k]).
__global__ __launch_bounds__(1024) void finalize1(
    const float* __restrict__ counts, const float* __restrict__ loss_sum,
    const float* __restrict__ ema_count, const float* __restrict__ usage,
    float* __restrict__ out) {
    const int k = threadIdx.x;
    const float cnt = counts[k];
    const float raw = 0.999f * ema_count[k] + 0.001f * cnt;
    const float p = cnt * (1.0f / 65536.0f);
    const float term = p * logf(p + 1e-10f);

    float v1 = raw, v2 = term;
#pragma unroll
    for (int off = 32; off; off >>= 1) {
        v1 += __shfl_down(v1, off, 64);
        v2 += __shfl_down(v2, off, 64);
    }
    __shared__ float r1[16], r2[16];
    __shared__ float s_n, s_plog;
    if ((k & 63) == 0) { r1[k >> 6] = v1; r2[k >> 6] = v2; }
    __syncthreads();
    if (k < 64) {
        float a = (k < 16) ? r1[k] : 0.0f;
        float b = (k < 16) ? r2[k] : 0.0f;
#pragma unroll
        for (int off = 8; off; off >>= 1) {
            a += __shfl_down(a, off, 64);
            b += __shfl_down(b, off, 64);
        }
        if (k == 0) { s_n = a; s_plog = b; }
    }
    __syncthreads();

    const float n = s_n;
    const float smoothed = (raw + 1e-5f) / (n + 1024.0f * 1e-5f) * n;
    out[NC_OFF + k] = smoothed;
    out[NU_OFF + k] = (usage[k] + (cnt > 0.0f ? 1.0f : 0.0f)) * 0.5f;
    if (k == 0) {
        const float lm = loss_sum[0] * (1.0f / 4194304.0f);
        out[SC_OFF + 0] = 0.25f * lm;    // commitment_loss
        out[SC_OFF + 1] = lm;            // codebook_loss
        out[SC_OFF + 2] = expf(-s_plog); // perplexity
    }
}

// block k: sum x rows of its token list (coalesced 256B rows), fused EMA.
__global__ __launch_bounds__(256) void gather2_kernel(
    const float* __restrict__ x, const float* __restrict__ counts,
    const int* __restrict__ offs, const int* __restrict__ list,
    const float* __restrict__ ema_weight, const float* __restrict__ out_nc,
    float* __restrict__ new_weight, float* __restrict__ new_embedding) {
    const int k    = blockIdx.x;
    const int wave = threadIdx.x >> 6;    // 0..3
    const int lane = threadIdx.x & 63;    // dimension
    const int cnt  = (int)counts[k];
    const int off  = offs[k];

    float acc = 0.0f;
    int i = wave;
    int tn = (i < cnt) ? list[off + i] : -1;
    while (i < cnt) {
        int t = tn;
        i += 4;
        tn = (i < cnt) ? list[off + i] : -1;   // prefetch next
        acc += x[(size_t)t * 64 + lane];
    }

    __shared__ float red[4][64];
    red[wave][lane] = acc;
    __syncthreads();
    if (wave == 0) {
        float s = (red[0][lane] + red[1][lane]) + (red[2][lane] + red[3][lane]);
        const float nc = out_nc[k];
        float w = 0.999f * ema_weight[(size_t)k * 64 + lane] + 0.001f * s;
        new_weight[(size_t)k * 64 + lane] = w;
        new_embedding[(size_t)k * 64 + lane] = w / nc;
    }
}

extern "C" void kernel_launch(void* const* d_in, const int* in_sizes, int n_in,
                              void* d_out, int out_size, void* d_ws, size_t ws_size,
                              hipStream_t stream) {
    const float* x          = (const float*)d_in[0];
    const float* emb        = (const float*)d_in[1];
    const float* ema_count  = (const float*)d_in[2];
    const float* ema_weight = (const float*)d_in[3];
    const float* usage      = (const float*)d_in[4];
    float* out = (float*)d_out;
    float* ws  = (float*)d_ws;

    float* counts = ws + WS_COUNTS;
    float* loss   = ws + WS_LOSS;
    float* hn     = ws + WS_HN;
    int*   idx    = (int*)(ws + WS_IDX);
    int*   offs   = (int*)(ws + WS_OFFS);
    int*   cursor = (int*)(ws + WS_CURSOR);
    int*   list   = (int*)(ws + WS_LIST);

    // ws is re-poisoned to 0xAA before every timed launch -> zero the
    // atomic regions (counts + loss). Everything else is fully written.
    (void)hipMemsetAsync(ws, 0, 1025 * sizeof(float), stream);

    hn_kernel<<<4, 256, 0, stream>>>(emb, hn);
    assign_fused<<<512, 256, 0, stream>>>(x, emb, hn, counts, loss, idx,
                                          out + Q_OFF);
    scan_kernel<<<1, 1024, 0, stream>>>(counts, offs, cursor);
    scatter_kernel<<<256, 256, 0, stream>>>(idx, cursor, list);
    finalize1<<<1, 1024, 0, stream>>>(counts, loss, ema_count, usage, out);
    gather2_kernel<<<1024, 256, 0, stream>>>(x, counts, offs, list, ema_weight,
                                             out + NC_OFF, out + NW_OFF,
                                             out + NE_OFF);
}